// Round 1
// baseline (387.726 us; speedup 1.0000x reference)
//
#include <hip/hip_runtime.h>

// Problem constants (B=2, S=2048, D=2048, H=16, DH=128)
#define S_ 2048
#define D_ 2048
#define H_ 16
#define DH_ 128

typedef __attribute__((ext_vector_type(8))) short short8;     // 8 bf16 (4 VGPRs) MFMA frag
typedef __attribute__((ext_vector_type(4))) float f32x4;      // MFMA accumulator
typedef __attribute__((ext_vector_type(8))) unsigned short ushort8;
typedef __attribute__((ext_vector_type(4))) unsigned short ushort4v;

// fp32 -> bf16 bits, round-to-nearest-even
__device__ __forceinline__ unsigned short f2bf(float f) {
  unsigned int u;
  __builtin_memcpy(&u, &f, 4);
  unsigned int lsb = (u >> 16) & 1u;
  u += 0x7fffu + lsb;
  return (unsigned short)(u >> 16);
}

// async global->LDS, 16B per lane; LDS dst = wave-uniform base + lane*16
__device__ __forceinline__ void gload_lds16(const void* g, void* l) {
  __builtin_amdgcn_global_load_lds(
      (const __attribute__((address_space(1))) unsigned int*)g,
      (__attribute__((address_space(3))) unsigned int*)l, 16, 0, 0);
}

// ---------------------------------------------------------------------------
// x (fp32) -> bf16, 8 elems/thread
__global__ void k_convert_x(const float* __restrict__ x, unsigned short* __restrict__ xb) {
  int idx = blockIdx.x * 256 + threadIdx.x;  // 1,048,576 threads
  const float4* xv = (const float4*)x;
  float4 a = xv[(size_t)idx * 2];
  float4 b = xv[(size_t)idx * 2 + 1];
  ushort8 o;
  o[0] = f2bf(a.x); o[1] = f2bf(a.y); o[2] = f2bf(a.z); o[3] = f2bf(a.w);
  o[4] = f2bf(b.x); o[5] = f2bf(b.y); o[6] = f2bf(b.z); o[7] = f2bf(b.w);
  *(ushort8*)(xb + (size_t)idx * 8) = o;
}

// ---------------------------------------------------------------------------
// W [K=2048][Nw] fp32 -> WT [Nw][2048] bf16, with RoPE rotation folded into
// columns n < rot_limit. Reference quirk: head h uses cos/sin row h (constant
// over sequence positions), so the rotation is a fixed per-head linear map.
// Tile: 32 k-rows x 128 n-cols (one full head per tile; boundaries align).
__global__ void k_prep_w(const float* __restrict__ W, const float* __restrict__ cosb,
                         const float* __restrict__ sinb, unsigned short* __restrict__ WT,
                         int Nw, int rot_limit) {
  __shared__ float tile[32][129];  // +1 pad: conflict-free column reads
  const int t = threadIdx.x;
  const int kt = blockIdx.x * 32, nt = blockIdx.y * 128;
#pragma unroll
  for (int i = 0; i < 4; ++i) {
    int q = i * 256 + t;            // 1024 float4 loads
    int kl = q >> 5, cq = q & 31;
    float4 v = *(const float4*)(W + (size_t)(kt + kl) * Nw + nt + cq * 4);
    tile[kl][cq * 4 + 0] = v.x; tile[kl][cq * 4 + 1] = v.y;
    tile[kl][cq * 4 + 2] = v.z; tile[kl][cq * 4 + 3] = v.w;
  }
  __syncthreads();
  const bool rot = nt < rot_limit;  // uniform per block (boundaries % 128 == 0)
#pragma unroll
  for (int i = 0; i < 16; ++i) {
    int f = i * 256 + t;
    int kl = f & 31, nl = f >> 5;   // nl in [0,128) = dim within head
    int ng = nt + nl;
    float val;
    if (rot) {
      int i0 = nl & 63;
      int h = (ng & 2047) >> 7;
      float c = cosb[h * 64 + i0], sn = sinb[h * 64 + i0];
      float re = tile[kl][i0], im = tile[kl][i0 + 64];
      val = (nl < 64) ? (re * c - im * sn) : (re * sn + im * c);
    } else {
      val = tile[kl][nl];
    }
    WT[(size_t)ng * 2048 + kt + kl] = f2bf(val);
  }
}

// ---------------------------------------------------------------------------
// V [bh][s][128] -> Vt [bh][d][s]  (so PV B-frags read kv-contiguous 16B)
__global__ void k_transpose_v(const unsigned short* __restrict__ V,
                              unsigned short* __restrict__ Vt) {
  __shared__ unsigned short tile[128][72];  // d-major, +8 pad
  const int t = threadIdx.x;
  const int sb = blockIdx.x * 64;
  const int bh = blockIdx.y;
  const unsigned short* Vp = V + (size_t)bh * S_ * DH_;
#pragma unroll
  for (int i = 0; i < 4; ++i) {
    int c8 = i * 256 + t;           // 1024 chunks of 8
    int sl = c8 >> 4, dc = c8 & 15;
    ushort8 v = *(const ushort8*)(Vp + (size_t)(sb + sl) * 128 + dc * 8);
#pragma unroll
    for (int j = 0; j < 8; ++j) tile[dc * 8 + j][sl] = v[j];
  }
  __syncthreads();
  unsigned short* Vtp = Vt + (size_t)bh * DH_ * S_;
#pragma unroll
  for (int i = 0; i < 8; ++i) {
    int q = i * 256 + t;            // 2048 quads
    int d = q >> 4, sq = q & 15;
    ushort4v o;
#pragma unroll
    for (int j = 0; j < 4; ++j) o[j] = tile[d][sq * 4 + j];
    *(ushort4v*)(Vtp + (size_t)d * S_ + sb + sq * 4) = o;
  }
}

// ---------------------------------------------------------------------------
// m97-style GEMM: C[MxN] = A[M][K=2048] * Bt[N][K=2048]^T, 128x128 tile,
// BK=64, 4 waves (2x2 of 64x64), global_load_lds w=16, XOR-swizzled LDS
// (swizzle applied to SOURCE addr + READ addr, linear LDS dest — rule #21).
// mode 0: scatter to Q/K/V head-major bf16 (+bias). mode 1: fp32 out (+bias).
__global__ __launch_bounds__(256) void k_gemm_bt(
    const unsigned short* __restrict__ A, const unsigned short* __restrict__ Bt,
    const float* __restrict__ bias, int mode,
    unsigned short* __restrict__ Qb, unsigned short* __restrict__ Kb,
    unsigned short* __restrict__ Vb, float* __restrict__ Co) {
  __shared__ unsigned short lds[16384];  // A tile 16KB | B tile 16KB
  const int t = threadIdx.x;
  const int l = t & 63, w = t >> 6;
  const int wr = w >> 1, wc = w & 1;
  const int tm = blockIdx.x * 128, tn = blockIdx.y * 128;
  f32x4 acc[4][4] = {};

  for (int kt = 0; kt < 32; ++kt) {
    __syncthreads();
#pragma unroll
    for (int i = 0; i < 4; ++i) {
      int cid = w * 4 + i;                  // wave-uniform LDS base
      int row = cid * 8 + (l >> 3);         // tile row this lane fills
      int slot = (l & 7) ^ (row & 7);       // pre-swizzled SOURCE slot
      gload_lds16(A + (size_t)(tm + row) * 2048 + kt * 64 + slot * 8,
                  lds + cid * 512);
      gload_lds16(Bt + (size_t)(tn + row) * 2048 + kt * 64 + slot * 8,
                  lds + 8192 + cid * 512);
    }
    __syncthreads();
#pragma unroll
    for (int kk = 0; kk < 2; ++kk) {
      short8 af[4], bf[4];
#pragma unroll
      for (int m = 0; m < 4; ++m) {
        int row = wr * 64 + m * 16 + (l & 15);
        int off = (kk * 64 + ((l >> 4) * 16)) ^ ((row & 7) << 4);
        af[m] = *(const short8*)((const char*)lds + row * 128 + off);
      }
#pragma unroll
      for (int n = 0; n < 4; ++n) {
        int row = wc * 64 + n * 16 + (l & 15);
        int off = (kk * 64 + ((l >> 4) * 16)) ^ ((row & 7) << 4);
        bf[n] = *(const short8*)((const char*)(lds + 8192) + row * 128 + off);
      }
#pragma unroll
      for (int m = 0; m < 4; ++m)
#pragma unroll
        for (int n = 0; n < 4; ++n)
          acc[m][n] = __builtin_amdgcn_mfma_f32_16x16x32_bf16(af[m], bf[n], acc[m][n], 0, 0, 0);
    }
  }

  // Epilogue. C/D layout: col = lane&15, row = (lane>>4)*4 + reg  [m89]
#pragma unroll
  for (int m = 0; m < 4; ++m) {
    int rbase = tm + wr * 64 + m * 16 + ((l >> 4) << 2);
#pragma unroll
    for (int n = 0; n < 4; ++n) {
      int colg = tn + wc * 64 + n * 16 + (l & 15);
      float bv = bias[colg];
#pragma unroll
      for (int j = 0; j < 4; ++j) {
        float v = acc[m][n][j] + bv;
        int r = rbase + j;
        if (mode == 0) {
          int reg = colg >> 11;               // 0=q, 1=k, 2=v
          int b = r >> 11, s = r & 2047;
          int h = (colg & 2047) >> 7, dh = colg & 127;
          size_t off = ((size_t)(b * H_ + h) * S_ + s) * DH_ + dh;
          unsigned short bv16 = f2bf(v);
          if (reg == 0) Qb[off] = bv16;
          else if (reg == 1) Kb[off] = bv16;
          else Vb[off] = bv16;
        } else {
          Co[(size_t)r * 2048 + colg] = v;
        }
      }
    }
  }
}

// ---------------------------------------------------------------------------
// Causal flash attention. Grid (qt 0..31, bh 0..31). 4 waves x 16 q-rows,
// KV tile = 64. K,Vt staged via global_load_lds (swizzled), softmax fully
// wave-parallel (16-lane shfl_xor reduce), P bounced via swizzled LDS.
__global__ __launch_bounds__(256) void k_attn(
    const unsigned short* __restrict__ Qb, const unsigned short* __restrict__ Kb,
    const unsigned short* __restrict__ Vt, unsigned short* __restrict__ Ob) {
  __shared__ unsigned short kls[8192];   // 64 rows x 256B (swz)
  __shared__ unsigned short vls[8192];   // 128 rows x 128B (swz)
  __shared__ unsigned short pls[4096];   // 4 waves x [16 x 64] bf16 (swz)
  const int t = threadIdx.x, l = t & 63, w = t >> 6;
  const int qt = blockIdx.x, bh = blockIdx.y;
  const int qb = qt * 64;
  const int b = bh >> 4, h = bh & 15;
  const unsigned short* Qp = Qb + (size_t)bh * S_ * DH_;
  const unsigned short* Kp = Kb + (size_t)bh * S_ * DH_;
  const unsigned short* Vp = Vt + (size_t)bh * DH_ * S_;

  // Q fragments held in registers for the whole block
  short8 qf[4];
  {
    int row = qb + w * 16 + (l & 15);
#pragma unroll
    for (int c = 0; c < 4; ++c)
      qf[c] = *(const short8*)(Qp + (size_t)row * 128 + c * 32 + ((l >> 4) * 8));
  }

  f32x4 o[8] = {};
  float mrow[4] = {-1e30f, -1e30f, -1e30f, -1e30f};
  float lrow[4] = {0.f, 0.f, 0.f, 0.f};
  const float scale = 0.08838834764831845f;  // 1/sqrt(128)

  for (int kvt = 0; kvt <= qt; ++kvt) {
    const int kvb = kvt * 64;
    __syncthreads();  // previous tile's reads done before restage
#pragma unroll
    for (int i = 0; i < 4; ++i) {
      int cid = w + i * 4;  // wave-uniform
      {  // K tile: 64 rows x 256B
        int row = cid * 4 + (l >> 4);
        int slot = (l & 15) ^ (row & 7);
        gload_lds16(Kp + (size_t)(kvb + row) * 128 + slot * 8, kls + cid * 512);
      }
      {  // V tile (from Vt): 128 rows x 128B
        int row = cid * 8 + (l >> 3);
        int slot = (l & 7) ^ (row & 7);
        gload_lds16(Vp + (size_t)row * S_ + kvb + slot * 8, vls + cid * 512);
      }
    }
    __syncthreads();  // staging complete (vmcnt(0) drained by barrier)

    // QK^T: scores 16x64 per wave
    f32x4 sc[4];
#pragma unroll
    for (int nb = 0; nb < 4; ++nb) {
      f32x4 sacc = {};
#pragma unroll
      for (int c = 0; c < 4; ++c) {
        int row = nb * 16 + (l & 15);
        int off = (c * 64 + ((l >> 4) * 16)) ^ ((row & 7) << 4);
        short8 kf = *(const short8*)((const char*)kls + row * 256 + off);
        sacc = __builtin_amdgcn_mfma_f32_16x16x32_bf16(qf[c], kf, sacc, 0, 0, 0);
      }
      sc[nb] = sacc;
    }

    // online softmax — all 64 lanes busy; rows reduce over 16-lane groups
    float fsc[4];
#pragma unroll
    for (int j = 0; j < 4; ++j) {
      int qrow = qb + w * 16 + ((l >> 4) << 2) + j;
      float xs[4];
      float xm = -1e30f;
#pragma unroll
      for (int nb = 0; nb < 4; ++nb) {
        int kv = kvb + nb * 16 + (l & 15);
        float x = sc[nb][j] * scale;
        if (kv > qrow) x = -1e30f;  // causal mask
        xs[nb] = x;
        xm = fmaxf(xm, x);
      }
#pragma unroll
      for (int msk = 8; msk >= 1; msk >>= 1) xm = fmaxf(xm, __shfl_xor(xm, msk));
      float newm = fmaxf(mrow[j], xm);
      float f = __expf(mrow[j] - newm);
      mrow[j] = newm;
      float rs = 0.f;
#pragma unroll
      for (int nb = 0; nb < 4; ++nb) {
        float p = __expf(xs[nb] - newm);
        xs[nb] = p;
        rs += p;
      }
#pragma unroll
      for (int msk = 8; msk >= 1; msk >>= 1) rs += __shfl_xor(rs, msk);
      lrow[j] = lrow[j] * f + rs;
      fsc[j] = f;
      // P -> LDS (bf16), swizzled; read back as PV A-frags (the transpose)
      int prow = ((l >> 4) << 2) + j;
#pragma unroll
      for (int nb = 0; nb < 4; ++nb) {
        int colb = (nb * 16 + (l & 15)) * 2;
        *(unsigned short*)((char*)pls + w * 2048 + prow * 128 +
                           (colb ^ ((prow & 7) << 4))) = f2bf(xs[nb]);
      }
    }
#pragma unroll
    for (int d = 0; d < 8; ++d) {
      o[d][0] *= fsc[0]; o[d][1] *= fsc[1]; o[d][2] *= fsc[2]; o[d][3] *= fsc[3];
    }
    __syncthreads();  // P visible/ordered before PV reads

    // PV: out 16x128 per wave
#pragma unroll
    for (int kc = 0; kc < 2; ++kc) {
      int prow = l & 15;
      int poff = (kc * 64 + ((l >> 4) * 16)) ^ ((prow & 7) << 4);
      short8 pa = *(const short8*)((const char*)pls + w * 2048 + prow * 128 + poff);
#pragma unroll
      for (int d = 0; d < 8; ++d) {
        int vrow = d * 16 + (l & 15);
        int voff = (kc * 64 + ((l >> 4) * 16)) ^ ((vrow & 7) << 4);
        short8 vf = *(const short8*)((const char*)vls + vrow * 128 + voff);
        o[d] = __builtin_amdgcn_mfma_f32_16x16x32_bf16(pa, vf, o[d], 0, 0, 0);
      }
    }
  }

  // normalize + write merged-head bf16 [b][s][h*128+d]
  float inv[4] = {1.f / lrow[0], 1.f / lrow[1], 1.f / lrow[2], 1.f / lrow[3]};
#pragma unroll
  for (int d = 0; d < 8; ++d) {
#pragma unroll
    for (int j = 0; j < 4; ++j) {
      int s = qb + w * 16 + ((l >> 4) << 2) + j;
      int col = h * 128 + d * 16 + (l & 15);
      Ob[((size_t)(b * S_ + s)) * D_ + col] = f2bf(o[d][j] * inv[j]);
    }
  }
}

// ---------------------------------------------------------------------------
extern "C" void kernel_launch(void* const* d_in, const int* in_sizes, int n_in,
                              void* d_out, int out_size, void* d_ws, size_t ws_size,
                              hipStream_t stream) {
  const float* x    = (const float*)d_in[0];
  const float* Wqkv = (const float*)d_in[1];
  const float* bqkv = (const float*)d_in[2];
  const float* Wout = (const float*)d_in[3];
  const float* bout = (const float*)d_in[4];
  const float* fcos = (const float*)d_in[5];
  const float* fsin = (const float*)d_in[6];
  // d_in[7] = mask: causal triu(1), hardcoded in k_attn
  float* out = (float*)d_out;

  // workspace layout (bytes): total 117,440,512
  char* ws = (char*)d_ws;
  unsigned short* xbf   = (unsigned short*)(ws);                       // 16 MB
  unsigned short* wqkvT = (unsigned short*)(ws + 16777216);            // 24 MB
  unsigned short* woutT = (unsigned short*)(ws + 41943040);            //  8 MB
  unsigned short* Qb    = (unsigned short*)(ws + 50331648);            // 16 MB
  unsigned short* Kb    = Qb + 8388608;
  unsigned short* Vb    = Kb + 8388608;
  unsigned short* Vtb   = Vb + 8388608;
  unsigned short* Ob    = xbf;  // alias: xbf dead after GEMM1

  hipLaunchKernelGGL(k_convert_x, dim3(4096), dim3(256), 0, stream, x, xbf);
  hipLaunchKernelGGL(k_prep_w, dim3(64, 48), dim3(256), 0, stream,
                     Wqkv, fcos, fsin, wqkvT, 6144, 4096);
  hipLaunchKernelGGL(k_prep_w, dim3(64, 16), dim3(256), 0, stream,
                     Wout, fcos, fsin, woutT, 2048, 0);
  hipLaunchKernelGGL(k_gemm_bt, dim3(32, 48), dim3(256), 0, stream,
                     xbf, wqkvT, bqkv, 0, Qb, Kb, Vb, (float*)nullptr);
  hipLaunchKernelGGL(k_transpose_v, dim3(32, 32), dim3(256), 0, stream, Vb, Vtb);
  hipLaunchKernelGGL(k_attn, dim3(32, 32), dim3(256), 0, stream, Qb, Kb, Vtb, Ob);
  hipLaunchKernelGGL(k_gemm_bt, dim3(32, 16), dim3(256), 0, stream,
                     Ob, woutT, bout, 1, (unsigned short*)nullptr,
                     (unsigned short*)nullptr, (unsigned short*)nullptr, out);
}

// Round 2
// 314.542 us; speedup vs baseline: 1.2327x; 1.2327x over previous
//
#include <hip/hip_runtime.h>

// Problem constants (B=2, S=2048, D=2048, H=16, DH=128)
#define S_ 2048
#define D_ 2048
#define H_ 16
#define DH_ 128

typedef __attribute__((ext_vector_type(8))) short short8;     // 8 bf16 (4 VGPRs) MFMA frag
typedef __attribute__((ext_vector_type(4))) float f32x4;      // MFMA accumulator
typedef __attribute__((ext_vector_type(8))) unsigned short ushort8;
typedef __attribute__((ext_vector_type(4))) unsigned short ushort4v;

// fp32 -> bf16 bits, round-to-nearest-even
__device__ __forceinline__ unsigned short f2bf(float f) {
  unsigned int u;
  __builtin_memcpy(&u, &f, 4);
  unsigned int lsb = (u >> 16) & 1u;
  u += 0x7fffu + lsb;
  return (unsigned short)(u >> 16);
}

// async global->LDS, 16B per lane; LDS dst = wave-uniform base + lane*16
__device__ __forceinline__ void gload_lds16(const void* g, void* l) {
  __builtin_amdgcn_global_load_lds(
      (const __attribute__((address_space(1))) unsigned int*)g,
      (__attribute__((address_space(3))) unsigned int*)l, 16, 0, 0);
}

// ---------------------------------------------------------------------------
// x (fp32) -> bf16, 8 elems/thread
__global__ void k_convert_x(const float* __restrict__ x, unsigned short* __restrict__ xb) {
  int idx = blockIdx.x * 256 + threadIdx.x;  // 1,048,576 threads
  const float4* xv = (const float4*)x;
  float4 a = xv[(size_t)idx * 2];
  float4 b = xv[(size_t)idx * 2 + 1];
  ushort8 o;
  o[0] = f2bf(a.x); o[1] = f2bf(a.y); o[2] = f2bf(a.z); o[3] = f2bf(a.w);
  o[4] = f2bf(b.x); o[5] = f2bf(b.y); o[6] = f2bf(b.z); o[7] = f2bf(b.w);
  *(ushort8*)(xb + (size_t)idx * 8) = o;
}

// ---------------------------------------------------------------------------
// W [K=2048][Nw] fp32 -> WT [Nw][2048] bf16, with RoPE rotation folded into
// columns n < rot_limit. Reference quirk: head h uses cos/sin row h (constant
// over sequence positions), so the rotation is a fixed per-head linear map.
__global__ void k_prep_w(const float* __restrict__ W, const float* __restrict__ cosb,
                         const float* __restrict__ sinb, unsigned short* __restrict__ WT,
                         int Nw, int rot_limit) {
  __shared__ float tile[32][129];  // +1 pad: conflict-free column reads
  const int t = threadIdx.x;
  const int kt = blockIdx.x * 32, nt = blockIdx.y * 128;
#pragma unroll
  for (int i = 0; i < 4; ++i) {
    int q = i * 256 + t;            // 1024 float4 loads
    int kl = q >> 5, cq = q & 31;
    float4 v = *(const float4*)(W + (size_t)(kt + kl) * Nw + nt + cq * 4);
    tile[kl][cq * 4 + 0] = v.x; tile[kl][cq * 4 + 1] = v.y;
    tile[kl][cq * 4 + 2] = v.z; tile[kl][cq * 4 + 3] = v.w;
  }
  __syncthreads();
  const bool rot = nt < rot_limit;  // uniform per block (boundaries % 128 == 0)
#pragma unroll
  for (int i = 0; i < 16; ++i) {
    int f = i * 256 + t;
    int kl = f & 31, nl = f >> 5;   // nl in [0,128) = dim within head
    int ng = nt + nl;
    float val;
    if (rot) {
      int i0 = nl & 63;
      int h = (ng & 2047) >> 7;
      float c = cosb[h * 64 + i0], sn = sinb[h * 64 + i0];
      float re = tile[kl][i0], im = tile[kl][i0 + 64];
      val = (nl < 64) ? (re * c - im * sn) : (re * sn + im * c);
    } else {
      val = tile[kl][nl];
    }
    WT[(size_t)ng * 2048 + kt + kl] = f2bf(val);
  }
}

// ---------------------------------------------------------------------------
// V [bh][s][128] -> Vt [bh][d][s]  (so PV B-frags read kv-contiguous 16B)
__global__ void k_transpose_v(const unsigned short* __restrict__ V,
                              unsigned short* __restrict__ Vt) {
  __shared__ unsigned short tile[128][72];  // d-major, +8 pad
  const int t = threadIdx.x;
  const int sb = blockIdx.x * 64;
  const int bh = blockIdx.y;
  const unsigned short* Vp = V + (size_t)bh * S_ * DH_;
#pragma unroll
  for (int i = 0; i < 4; ++i) {
    int c8 = i * 256 + t;           // 1024 chunks of 8
    int sl = c8 >> 4, dc = c8 & 15;
    ushort8 v = *(const ushort8*)(Vp + (size_t)(sb + sl) * 128 + dc * 8);
#pragma unroll
    for (int j = 0; j < 8; ++j) tile[dc * 8 + j][sl] = v[j];
  }
  __syncthreads();
  unsigned short* Vtp = Vt + (size_t)bh * DH_ * S_;
#pragma unroll
  for (int i = 0; i < 8; ++i) {
    int q = i * 256 + t;            // 2048 quads
    int d = q >> 4, sq = q & 15;
    ushort4v o;
#pragma unroll
    for (int j = 0; j < 4; ++j) o[j] = tile[d][sq * 4 + j];
    *(ushort4v*)(Vtp + (size_t)d * S_ + sb + sq * 4) = o;
  }
}

// ---------------------------------------------------------------------------
// m97-style GEMM: C[MxN] = A[M][K=2048] * Bt[N][K=2048]^T, 128x128 tile,
// BK=64, 4 waves (2x2 of 64x64), global_load_lds w=16, XOR-swizzled LDS.
// mode 0: scatter to Q/K/V head-major bf16 (+bias, Q pre-scaled by 1/sqrt(DH)).
// mode 1: fp32 out (+bias).
__global__ __launch_bounds__(256) void k_gemm_bt(
    const unsigned short* __restrict__ A, const unsigned short* __restrict__ Bt,
    const float* __restrict__ bias, int mode,
    unsigned short* __restrict__ Qb, unsigned short* __restrict__ Kb,
    unsigned short* __restrict__ Vb, float* __restrict__ Co) {
  __shared__ unsigned short lds[16384];  // A tile 16KB | B tile 16KB
  const int t = threadIdx.x;
  const int l = t & 63, w = t >> 6;
  const int wr = w >> 1, wc = w & 1;
  const int tm = blockIdx.x * 128, tn = blockIdx.y * 128;
  f32x4 acc[4][4] = {};

  for (int kt = 0; kt < 32; ++kt) {
    __syncthreads();
#pragma unroll
    for (int i = 0; i < 4; ++i) {
      int cid = w * 4 + i;                  // wave-uniform LDS base
      int row = cid * 8 + (l >> 3);         // tile row this lane fills
      int slot = (l & 7) ^ (row & 7);       // pre-swizzled SOURCE slot
      gload_lds16(A + (size_t)(tm + row) * 2048 + kt * 64 + slot * 8,
                  lds + cid * 512);
      gload_lds16(Bt + (size_t)(tn + row) * 2048 + kt * 64 + slot * 8,
                  lds + 8192 + cid * 512);
    }
    __syncthreads();
#pragma unroll
    for (int kk = 0; kk < 2; ++kk) {
      short8 af[4], bf[4];
#pragma unroll
      for (int m = 0; m < 4; ++m) {
        int row = wr * 64 + m * 16 + (l & 15);
        int off = (kk * 64 + ((l >> 4) * 16)) ^ ((row & 7) << 4);
        af[m] = *(const short8*)((const char*)lds + row * 128 + off);
      }
#pragma unroll
      for (int n = 0; n < 4; ++n) {
        int row = wc * 64 + n * 16 + (l & 15);
        int off = (kk * 64 + ((l >> 4) * 16)) ^ ((row & 7) << 4);
        bf[n] = *(const short8*)((const char*)(lds + 8192) + row * 128 + off);
      }
#pragma unroll
      for (int m = 0; m < 4; ++m)
#pragma unroll
        for (int n = 0; n < 4; ++n)
          acc[m][n] = __builtin_amdgcn_mfma_f32_16x16x32_bf16(af[m], bf[n], acc[m][n], 0, 0, 0);
    }
  }

  // Epilogue. C/D layout: col = lane&15, row = (lane>>4)*4 + reg  [m89]
#pragma unroll
  for (int m = 0; m < 4; ++m) {
    int rbase = tm + wr * 64 + m * 16 + ((l >> 4) << 2);
#pragma unroll
    for (int n = 0; n < 4; ++n) {
      int colg = tn + wc * 64 + n * 16 + (l & 15);
      float bv = bias[colg];
#pragma unroll
      for (int j = 0; j < 4; ++j) {
        float v = acc[m][n][j] + bv;
        int r = rbase + j;
        if (mode == 0) {
          int reg = colg >> 11;               // 0=q, 1=k, 2=v
          int b = r >> 11, s = r & 2047;
          int h = (colg & 2047) >> 7, dh = colg & 127;
          size_t off = ((size_t)(b * H_ + h) * S_ + s) * DH_ + dh;
          if (reg == 0) Qb[off] = f2bf(v * 0.08838834764831845f);  // fold 1/sqrt(DH)
          else if (reg == 1) Kb[off] = f2bf(v);
          else Vb[off] = f2bf(v);
        } else {
          Co[(size_t)r * 2048 + colg] = v;
        }
      }
    }
  }
}

// ---------------------------------------------------------------------------
// Causal flash attention, load-balanced + double-buffered staging.
// Grid (pair 0..15, bh 0..31): block handles q-tiles {pair, 31-pair} -> every
// block does exactly 33 kv-tile iterations. 4 waves x 16 q-rows, KVBLK=64.
// K/V double-buffered: next tile's global_load_lds issued before QK+softmax,
// drained by the mid-iter barrier (latency hidden under compute).
__global__ __launch_bounds__(256) void k_attn(
    const unsigned short* __restrict__ Qb, const unsigned short* __restrict__ Kb,
    const unsigned short* __restrict__ Vt, unsigned short* __restrict__ Ob) {
  __shared__ unsigned short kls[2][8192];   // 2 x 64 rows x 256B (swz)
  __shared__ unsigned short vls[2][8192];   // 2 x 128 rows x 128B (swz)
  __shared__ unsigned short pls[4096];      // 4 waves x [16 x 64] bf16 (swz)
  const int t = threadIdx.x, l = t & 63, w = t >> 6;
  const int pairi = blockIdx.x, bh = blockIdx.y;
  const int b = bh >> 4, h = bh & 15;
  const int rb = (l >> 4) << 2;
  const unsigned short* Qp = Qb + (size_t)bh * S_ * DH_;
  const unsigned short* Kp = Kb + (size_t)bh * S_ * DH_;
  const unsigned short* Vp = Vt + (size_t)bh * DH_ * S_;

#pragma unroll 1
  for (int half = 0; half < 2; ++half) {
    const int qt = half ? (31 - pairi) : pairi;
    const int qb = qt * 64;

    // Q fragments in registers (pre-scaled by 1/sqrt(DH) at GEMM1 epilogue)
    short8 qf[4];
    {
      int row = qb + w * 16 + (l & 15);
#pragma unroll
      for (int c = 0; c < 4; ++c)
        qf[c] = *(const short8*)(Qp + (size_t)row * 128 + c * 32 + ((l >> 4) * 8));
    }

    f32x4 o[8] = {};
    float mrow[4] = {-1e30f, -1e30f, -1e30f, -1e30f};
    float lrow[4] = {0.f, 0.f, 0.f, 0.f};

    // prologue: stage kv-tile 0 into buffer 0
#pragma unroll
    for (int i = 0; i < 4; ++i) {
      int cid = w + i * 4;  // wave-uniform
      int krow = cid * 4 + (l >> 4);
      int kslot = (l & 15) ^ (krow & 7);
      gload_lds16(Kp + (size_t)krow * 128 + kslot * 8, &kls[0][cid * 512]);
      int vrow = cid * 8 + (l >> 3);
      int vslot = (l & 7) ^ (vrow & 7);
      gload_lds16(Vp + (size_t)vrow * S_ + vslot * 8, &vls[0][cid * 512]);
    }
    __syncthreads();

#pragma unroll 1
    for (int kvt = 0; kvt <= qt; ++kvt) {
      const int kvb = kvt * 64;
      const int cur = kvt & 1;

      // issue next tile's staging (drained at the mid-iter barrier)
      if (kvt < qt) {
        const int kvb2 = kvb + 64;
#pragma unroll
        for (int i = 0; i < 4; ++i) {
          int cid = w + i * 4;
          int krow = cid * 4 + (l >> 4);
          int kslot = (l & 15) ^ (krow & 7);
          gload_lds16(Kp + (size_t)(kvb2 + krow) * 128 + kslot * 8,
                      &kls[cur ^ 1][cid * 512]);
          int vrow = cid * 8 + (l >> 3);
          int vslot = (l & 7) ^ (vrow & 7);
          gload_lds16(Vp + (size_t)vrow * S_ + kvb2 + vslot * 8,
                      &vls[cur ^ 1][cid * 512]);
        }
      }

      // QK^T: scores 16x64 per wave
      f32x4 sc[4];
      __builtin_amdgcn_s_setprio(1);
#pragma unroll
      for (int nb = 0; nb < 4; ++nb) {
        f32x4 sacc = {};
#pragma unroll
        for (int c = 0; c < 4; ++c) {
          int row = nb * 16 + (l & 15);
          int off = (c * 64 + ((l >> 4) * 16)) ^ ((row & 7) << 4);
          short8 kf = *(const short8*)((const char*)kls[cur] + row * 256 + off);
          sacc = __builtin_amdgcn_mfma_f32_16x16x32_bf16(qf[c], kf, sacc, 0, 0, 0);
        }
        sc[nb] = sacc;
      }
      __builtin_amdgcn_s_setprio(0);

      // online softmax: 4 independent 16-lane reduce chains, mask diag only
      float xs[4][4], xm[4];
      const bool diag = (kvt == qt);
#pragma unroll
      for (int j = 0; j < 4; ++j) {
        float m0 = -1e30f;
#pragma unroll
        for (int nb = 0; nb < 4; ++nb) {
          float x = sc[nb][j];
          if (diag) {
            int kv = kvb + nb * 16 + (l & 15);
            if (kv > qb + w * 16 + rb + j) x = -1e30f;  // causal mask
          }
          xs[j][nb] = x;
          m0 = fmaxf(m0, x);
        }
        xm[j] = m0;
      }
#pragma unroll
      for (int msk = 8; msk >= 1; msk >>= 1)
#pragma unroll
        for (int j = 0; j < 4; ++j) xm[j] = fmaxf(xm[j], __shfl_xor(xm[j], msk));

      // T13 defer-max: skip O-rescale unless max grew by > 8
      bool grow = false;
#pragma unroll
      for (int j = 0; j < 4; ++j) grow |= (xm[j] > mrow[j] + 8.f);
      if (__any(grow)) {
        float fsc[4];
#pragma unroll
        for (int j = 0; j < 4; ++j) {
          float nm = fmaxf(mrow[j], xm[j]);
          fsc[j] = __expf(mrow[j] - nm);
          mrow[j] = nm;
        }
#pragma unroll
        for (int d = 0; d < 8; ++d) {
          o[d][0] *= fsc[0]; o[d][1] *= fsc[1]; o[d][2] *= fsc[2]; o[d][3] *= fsc[3];
        }
#pragma unroll
        for (int j = 0; j < 4; ++j) lrow[j] *= fsc[j];
      }
      float rs[4];
#pragma unroll
      for (int j = 0; j < 4; ++j) {
        float s = 0.f;
#pragma unroll
        for (int nb = 0; nb < 4; ++nb) {
          float p = __expf(xs[j][nb] - mrow[j]);  // bounded by e^8
          xs[j][nb] = p;
          s += p;
        }
        rs[j] = s;
      }
#pragma unroll
      for (int msk = 8; msk >= 1; msk >>= 1)
#pragma unroll
        for (int j = 0; j < 4; ++j) rs[j] += __shfl_xor(rs[j], msk);
#pragma unroll
      for (int j = 0; j < 4; ++j) lrow[j] += rs[j];

      // P -> LDS (bf16), swizzled; read back as PV A-frags (the transpose)
#pragma unroll
      for (int j = 0; j < 4; ++j) {
        int prow = rb + j;
#pragma unroll
        for (int nb = 0; nb < 4; ++nb) {
          int colb = (nb * 16 + (l & 15)) * 2;
          *(unsigned short*)((char*)pls + w * 2048 + prow * 128 +
                             (colb ^ ((prow & 7) << 4))) = f2bf(xs[j][nb]);
        }
      }
      __syncthreads();  // P ready; next-tile staging drained (hidden)

      // PV: out 16x128 per wave
      __builtin_amdgcn_s_setprio(1);
#pragma unroll
      for (int kc = 0; kc < 2; ++kc) {
        int prow = l & 15;
        int poff = (kc * 64 + ((l >> 4) * 16)) ^ ((prow & 7) << 4);
        short8 pa = *(const short8*)((const char*)pls + w * 2048 + prow * 128 + poff);
#pragma unroll
        for (int d = 0; d < 8; ++d) {
          int vrow = d * 16 + (l & 15);
          int voff = (kc * 64 + ((l >> 4) * 16)) ^ ((vrow & 7) << 4);
          short8 vf = *(const short8*)((const char*)vls[cur] + vrow * 128 + voff);
          o[d] = __builtin_amdgcn_mfma_f32_16x16x32_bf16(pa, vf, o[d], 0, 0, 0);
        }
      }
      __builtin_amdgcn_s_setprio(0);
      __syncthreads();  // all reads of buf[cur] + pls done -> reusable
    }

    // normalize + write merged-head bf16 [b][s][h*128+d]
    float inv[4];
#pragma unroll
    for (int j = 0; j < 4; ++j) inv[j] = 1.f / lrow[j];
#pragma unroll
    for (int d = 0; d < 8; ++d) {
#pragma unroll
      for (int j = 0; j < 4; ++j) {
        int s = qb + w * 16 + rb + j;
        int col = h * 128 + d * 16 + (l & 15);
        Ob[((size_t)(b * S_ + s)) * D_ + col] = f2bf(o[d][j] * inv[j]);
      }
    }
  }
}

// ---------------------------------------------------------------------------
extern "C" void kernel_launch(void* const* d_in, const int* in_sizes, int n_in,
                              void* d_out, int out_size, void* d_ws, size_t ws_size,
                              hipStream_t stream) {
  const float* x    = (const float*)d_in[0];
  const float* Wqkv = (const float*)d_in[1];
  const float* bqkv = (const float*)d_in[2];
  const float* Wout = (const float*)d_in[3];
  const float* bout = (const float*)d_in[4];
  const float* fcos = (const float*)d_in[5];
  const float* fsin = (const float*)d_in[6];
  // d_in[7] = mask: causal triu(1), hardcoded in k_attn
  float* out = (float*)d_out;

  // workspace layout (bytes): total 117,440,512
  char* ws = (char*)d_ws;
  unsigned short* xbf   = (unsigned short*)(ws);                       // 16 MB
  unsigned short* wqkvT = (unsigned short*)(ws + 16777216);            // 24 MB
  unsigned short* woutT = (unsigned short*)(ws + 41943040);            //  8 MB
  unsigned short* Qb    = (unsigned short*)(ws + 50331648);            // 16 MB
  unsigned short* Kb    = Qb + 8388608;
  unsigned short* Vb    = Kb + 8388608;
  unsigned short* Vtb   = Vb + 8388608;
  unsigned short* Ob    = xbf;  // alias: xbf dead after GEMM1

  hipLaunchKernelGGL(k_convert_x, dim3(4096), dim3(256), 0, stream, x, xbf);
  hipLaunchKernelGGL(k_prep_w, dim3(64, 48), dim3(256), 0, stream,
                     Wqkv, fcos, fsin, wqkvT, 6144, 4096);
  hipLaunchKernelGGL(k_prep_w, dim3(64, 16), dim3(256), 0, stream,
                     Wout, fcos, fsin, woutT, 2048, 0);
  hipLaunchKernelGGL(k_gemm_bt, dim3(32, 48), dim3(256), 0, stream,
                     xbf, wqkvT, bqkv, 0, Qb, Kb, Vb, (float*)nullptr);
  hipLaunchKernelGGL(k_transpose_v, dim3(32, 32), dim3(256), 0, stream, Vb, Vtb);
  hipLaunchKernelGGL(k_attn, dim3(16, 32), dim3(256), 0, stream, Qb, Kb, Vtb, Ob);
  hipLaunchKernelGGL(k_gemm_bt, dim3(32, 16), dim3(256), 0, stream,
                     Ob, woutT, bout, 1, (unsigned short*)nullptr,
                     (unsigned short*)nullptr, (unsigned short*)nullptr, out);
}